// Round 4
// baseline (1086.395 us; speedup 1.0000x reference)
//
#include <hip/hip_runtime.h>

// GCN-VAE forward, fp32 pipeline, dtype-adaptive inputs, fp32 outputs.
// flag[0] = bf16-view NaN patterns in x sample   (>64        -> float inputs are fp32)
// flag[1] = zero hi-words in edge-pair sample    (>DET_ES/2  -> edge_index is int64)
// flag[2] = overflow-edge count (ELL slots exceeded; handled by k_spill)
// Round 7: sliced k_build re-read the dst stream 16x (451MB FETCH measured; NT made
// it worse by defeating cache absorption). Replaced with single-pass counting-sort
// partition: k_hist (exact counts) -> k_scan (prefix) -> k_part (LDS-staged 2KB
// coalesced bucket flushes) -> k_build2 x2 (one slice per XCD; 3.2MB window truly
// L2-resident). Edge pipeline traffic ~340MB vs 745MB before.

#define NEG 0.01f
#define GS 64        // g row stride (floats) -> 256B rows
#define ELLS 64      // ELL slots per node
#define NB 16        // partition buckets == dst slices
#define SPILL_CAP 65536

// detect sampling: 1024 chunks x 1024 words/pairs per side
#define DET_ES (1024 * 1024)
#define IS64_THRESH (DET_ES / 2)

// meta layout (ints): [k*16] bcount_k (padded) | [256+k] boffs_k | [288+k] bend_k |
// [512+k*16] gptr_k (padded write pointers)
#define META_INTS 1024

typedef int vint2 __attribute__((ext_vector_type(2)));

static __device__ __forceinline__ float bf2f(unsigned short u) {
    return __uint_as_float(((unsigned)u) << 16);
}
static __device__ __forceinline__ float leaky(float a) { return (a >= 0.f) ? a : NEG * a; }

__global__ void k_zero(int* __restrict__ indeg, int* __restrict__ flag,
                       int* __restrict__ meta, int n) {
    int i = blockIdx.x * 256 + threadIdx.x;
    if (i < n) indeg[i] = 0;
    if (blockIdx.x == 0) {
        for (int j = threadIdx.x; j < META_INTS; j += 256) meta[j] = 0;
        if (threadIdx.x == 0) { flag[0] = 0; flag[1] = 0; flag[2] = 0; }
    }
}

// Sampled dtype detection. waves 0..1023 sample x words, 1024..2047 edge hi-words.
__global__ void k_detect(const unsigned* __restrict__ x, long xwords,
                         const unsigned* __restrict__ ei, long epairs,
                         int* __restrict__ flag) {
    int gw = (blockIdx.x * 256 + threadIdx.x) >> 6;  // 0..2047
    int lane = threadIdx.x & 63;
    int side = gw >> 10;
    int ch = gw & 1023;
    int c = 0;
    if (side == 0) {
        long step = xwords >> 10;
        long base = (long)ch * step;
        if (base + 1024 > xwords) base = xwords > 1024 ? xwords - 1024 : 0;
#pragma unroll
        for (int t = 0; t < 16; t++) {
            long idx = base + t * 64 + lane;
            if (idx < xwords) {
                unsigned w = x[idx];
                if (((w >> 23) & 0xFFu) == 0xFFu || ((w >> 7) & 0xFFu) == 0xFFu) c++;
            }
        }
        for (int k = 32; k; k >>= 1) c += __shfl_xor(c, k);
        if (lane == 0 && c) atomicAdd(&flag[0], c);
    } else {
        long step = epairs >> 10;
        long base = (long)ch * step;
        if (base + 1024 > epairs) base = epairs > 1024 ? epairs - 1024 : 0;
#pragma unroll
        for (int t = 0; t < 16; t++) {
            long idx = base + t * 64 + lane;
            if (idx < epairs && ei[2 * idx + 1] == 0u) c++;
        }
        for (int k = 32; k; k >>= 1) c += __shfl_xor(c, k);
        if (lane == 0 && c) atomicAdd(&flag[1], c);
    }
}

// Exact per-bucket histogram of dst (one pass, LDS-aggregated).
__global__ __launch_bounds__(256) void k_hist(const int* __restrict__ ei,
                                              const int* __restrict__ flag,
                                              int* __restrict__ meta, int E, int N) {
    __shared__ int lh[NB];
    if (threadIdx.x < NB) lh[threadIdx.x] = 0;
    __syncthreads();
    bool is64 = flag[1] > IS64_THRESH;
    unsigned usw = ((unsigned)N + NB - 1) / NB;
    const long stride = 1024L * 256;
    if (is64) {
        const int2* p = (const int2*)ei;
        for (long e = (long)blockIdx.x * 256 + threadIdx.x; e < E; e += stride) {
            int d = p[E + e].x;
            if ((unsigned)d < (unsigned)N) atomicAdd(&lh[(unsigned)d / usw], 1);
        }
    } else {
        for (long e = (long)blockIdx.x * 256 + threadIdx.x; e < E; e += stride) {
            int d = ei[E + e];
            if ((unsigned)d < (unsigned)N) atomicAdd(&lh[(unsigned)d / usw], 1);
        }
    }
    __syncthreads();
    if (threadIdx.x < NB && lh[threadIdx.x]) atomicAdd(&meta[threadIdx.x * 16], lh[threadIdx.x]);
}

// 16-element prefix sum -> bucket offsets + write pointers.
__global__ void k_scan(int* __restrict__ meta) {
    if (threadIdx.x == 0) {
        int acc = 0;
        for (int k = 0; k < NB; k++) {
            int c = meta[k * 16];
            meta[256 + k] = acc;        // boffs
            meta[512 + k * 16] = acc;   // gptr
            acc += c;
            meta[288 + k] = acc;        // bend
        }
    }
}

// Single-pass partition of edges into NB dst-range buckets.
// LDS staging: 16 buckets x 512 int2 (64KB); flush 256-entry (2KB) coalesced
// chunks claimed by one global atomic each.
__global__ __launch_bounds__(256) void k_part(const int* __restrict__ ei,
                                              const int* __restrict__ flag,
                                              int* __restrict__ meta,
                                              int2* __restrict__ bucket, int E, int N) {
    __shared__ int2 buf[NB][512];
    __shared__ int lcnt[NB];
    __shared__ int lbase;
    if (threadIdx.x < NB) lcnt[threadIdx.x] = 0;
    __syncthreads();
    bool is64 = flag[1] > IS64_THRESH;
    unsigned usw = ((unsigned)N + NB - 1) / NB;
    int nsteps = (E + 2048 * 256 - 1) / (2048 * 256);
    for (int step = 0; step < nsteps; step++) {
        long e = (long)(step * 2048 + blockIdx.x) * 256 + threadIdx.x;
        int b = -1;
        int2 sd;
        if (e < E) {
            int src, d;
            if (is64) {
                const int2* p = (const int2*)ei;
                src = p[e].x;
                d = p[E + e].x;
            } else {
                src = ei[e];
                d = ei[E + e];
            }
            if ((unsigned)d < (unsigned)N) {
                b = (int)((unsigned)d / usw);
                sd = make_int2(src, d);
            }
        }
        if (b >= 0) {
            int p = atomicAdd(&lcnt[b], 1);  // max 255 remainder + 256 pushes = 511 < 512
            buf[b][p] = sd;
        }
        __syncthreads();
        for (int k = 0; k < NB; k++) {
            int cnt = lcnt[k];  // uniform (post-barrier)
            if (cnt >= 256) {
                if (threadIdx.x == 0) lbase = atomicAdd(&meta[512 + k * 16], 256);
                __syncthreads();
                bucket[lbase + threadIdx.x] = buf[k][threadIdx.x];
                int rem = cnt - 256;
                int2 r;
                if (threadIdx.x < rem) r = buf[k][256 + threadIdx.x];
                __syncthreads();
                if (threadIdx.x < rem) buf[k][threadIdx.x] = r;
                if (threadIdx.x == 0) lcnt[k] = rem;
                __syncthreads();
            }
        }
    }
    // drain remainders (<256 each)
    for (int k = 0; k < NB; k++) {
        int cnt = lcnt[k];
        if (cnt > 0) {
            if (threadIdx.x == 0) lbase = atomicAdd(&meta[512 + k * 16], cnt);
            __syncthreads();
            if (threadIdx.x < cnt) bucket[lbase + threadIdx.x] = buf[k][threadIdx.x];
            __syncthreads();
        }
    }
}

// ELL build from buckets. One launch per pass; pass p handles slices p*8..p*8+7,
// slice s on XCD (s&7) via blockIdx%8 round-robin: 3.2MB ELL window + 50KB indeg
// stays L2-resident. Bucket stream is truly read-once -> non-temporal.
__global__ __launch_bounds__(256) void k_build2(const int2* __restrict__ bucket,
                                                const int* __restrict__ meta,
                                                int* __restrict__ indeg,
                                                int* __restrict__ ebuf,
                                                int2* __restrict__ spill,
                                                int* __restrict__ flag, int N, int pass) {
    int s = pass * 8 + (blockIdx.x & 7);
    int q = blockIdx.x >> 3;  // 0..511
    int lo = meta[256 + s];
    int hi = meta[288 + s];
    for (int idx = lo + q * 256 + threadIdx.x; idx < hi; idx += 512 * 256) {
        vint2 t = __builtin_nontemporal_load((const vint2*)&bucket[idx]);
        int src = t.x;
        int d = t.y;
        if ((unsigned)src >= (unsigned)N) continue;
        int c = atomicAdd(&indeg[d], 1);
        if (c < ELLS) {
            ebuf[(size_t)d * ELLS + c] = src;
        } else {
            int o = atomicAdd(&flag[2], 1);
            if (o < SPILL_CAP) spill[o] = make_int2(src, d);
        }
    }
}

__global__ void k_dinv(const int* __restrict__ indeg, float* __restrict__ dinv, int n) {
    int i = blockIdx.x * 256 + threadIdx.x;
    if (i < n) dinv[i] = rsqrtf(1.0f + (float)indeg[i]);  // deg includes self loop
}

// convert the 16 weight/bias arrays into one fp32 block; block b handles array b.
struct CW {
    const void* src[16];
    int off[16];
    int n[16];
};
__global__ void k_convw(CW cw, float* __restrict__ dst, const int* __restrict__ flag) {
    int b = blockIdx.x;
    bool isf = flag[0] > 64;
    const float* sf = (const float*)cw.src[b];
    const unsigned short* sh = (const unsigned short*)cw.src[b];
    float* d = dst + cw.off[b];
    int n = cw.n[b];
    for (int i = threadIdx.x; i < n; i += 256) d[i] = isf ? sf[i] : bf2f(sh[i]);
}

// weight-block offsets (floats)
#define O_WG 0
#define O_BG 2500
#define O_WE1 2550
#define O_BE1 4550
#define O_WE2 4590
#define O_BE2 5790
#define O_WE3 5820
#define O_BE3 6420
#define O_WFC 6440
#define O_BFC 6540
#define O_WD1 6550
#define O_BD1 6750
#define O_WD2 6770
#define O_BD2 7570
#define O_WD3 7610
#define O_BD3 9610
#define W_TOT 9660

// g[i] = (x[i,100:150] @ Wg.T) * dinv[i]  -> fp32, stride GS
__global__ __launch_bounds__(256) void k_g(const void* __restrict__ xv,
                                           const float* __restrict__ W,
                                           const float* __restrict__ dinv,
                                           const int* __restrict__ flag,
                                           float* __restrict__ g, int n) {
    int i = blockIdx.x * 256 + threadIdx.x;
    if (i >= n) return;
    bool isf = flag[0] > 64;
    float xr[50];
    if (isf) {
        const float* p = (const float*)xv + (size_t)i * 150 + 100;
#pragma unroll
        for (int k = 0; k < 50; k++) xr[k] = p[k];
    } else {
        const unsigned short* p = (const unsigned short*)xv + (size_t)i * 150 + 100;
#pragma unroll
        for (int k = 0; k < 50; k++) xr[k] = bf2f(p[k]);
    }
    const float* Wg = W + O_WG;
    float di = dinv[i];
    float* gr = g + (size_t)i * GS;
#pragma unroll
    for (int f = 0; f < 50; f += 2) {
        float a0 = 0.f, a1 = 0.f;
#pragma unroll
        for (int p = 0; p < 50; p++) {
            a0 += Wg[f * 50 + p] * xr[p];
            a1 += Wg[(f + 1) * 50 + p] * xr[p];
        }
        gr[f] = a0 * di;
        gr[f + 1] = a1 * di;
    }
}

// wave per node: lane f accumulates feature f over ELL edges; 8-way ILP.
__global__ __launch_bounds__(256) void k_gather(const float* __restrict__ g,
                                                const int* __restrict__ indeg,
                                                const int* __restrict__ ebuf,
                                                const float* __restrict__ dinv,
                                                const float* __restrict__ W,
                                                float* __restrict__ h1, int n) {
    int wid = threadIdx.x >> 6;
    int lane = threadIdx.x & 63;
    int i = blockIdx.x * 4 + wid;
    if (i >= n) return;
    int fc = lane < 50 ? lane : 49;  // clamp: lanes 50..63 never stored
    int cnt = indeg[i];
    if (cnt > ELLS) cnt = ELLS;
    float di = dinv[i];
    int ev = (lane < cnt) ? ebuf[(size_t)i * ELLS + lane] : 0;
    float a0 = g[(size_t)i * GS + fc];  // self-loop term (g pre-scaled by dinv[src])
    float a1 = 0.f, a2 = 0.f, a3 = 0.f, a4 = 0.f, a5 = 0.f, a6 = 0.f, a7 = 0.f;
    int m = 0;
    for (; m + 7 < cnt; m += 8) {
        int j0 = __shfl(ev, m);
        int j1 = __shfl(ev, m + 1);
        int j2 = __shfl(ev, m + 2);
        int j3 = __shfl(ev, m + 3);
        int j4 = __shfl(ev, m + 4);
        int j5 = __shfl(ev, m + 5);
        int j6 = __shfl(ev, m + 6);
        int j7 = __shfl(ev, m + 7);
        a0 += g[(size_t)j0 * GS + fc];
        a1 += g[(size_t)j1 * GS + fc];
        a2 += g[(size_t)j2 * GS + fc];
        a3 += g[(size_t)j3 * GS + fc];
        a4 += g[(size_t)j4 * GS + fc];
        a5 += g[(size_t)j5 * GS + fc];
        a6 += g[(size_t)j6 * GS + fc];
        a7 += g[(size_t)j7 * GS + fc];
    }
    for (; m < cnt; m++) {
        int j = __shfl(ev, m);
        a0 += g[(size_t)j * GS + fc];
    }
    if (lane < 50) {
        float h = (((a0 + a1) + (a2 + a3)) + ((a4 + a5) + (a6 + a7))) * di + W[O_BG + lane];
        h1[(size_t)i * 50 + lane] = h;
    }
}

// overflow edges (deg > ELLS): atomic-add their contribution into h1.
__global__ void k_spill(const int2* __restrict__ spill, const int* __restrict__ flag,
                        const float* __restrict__ g, const float* __restrict__ dinv,
                        float* __restrict__ h1) {
    int nov = flag[2];
    if (nov > SPILL_CAP) nov = SPILL_CAP;
    int lane = threadIdx.x & 63;
    int wave = (blockIdx.x * 256 + threadIdx.x) >> 6;
    for (int e = wave; e < nov; e += gridDim.x * 4) {
        int2 sd = spill[e];
        if (lane < 50)
            atomicAdd(&h1[(size_t)sd.y * 50 + lane], g[(size_t)sd.x * GS + lane] * dinv[sd.y]);
    }
}

// ---- MLP split: each kernel has <16KB code and <8KB scalar weight stream ----

// e1: t1[i,0:40] = leaky(h1[i,:] @ We1.T + be1)
__global__ __launch_bounds__(256) void k_e1(const float* __restrict__ h1,
                                            const float* __restrict__ W,
                                            float* __restrict__ t1, int n) {
    int i = blockIdx.x * 256 + threadIdx.x;
    if (i >= n) return;
    float v0[50];
    const float2* hr = (const float2*)(h1 + (size_t)i * 50);
#pragma unroll
    for (int p = 0; p < 25; p++) {
        float2 q = hr[p];
        v0[2 * p] = q.x;
        v0[2 * p + 1] = q.y;
    }
    float o[40];
#pragma unroll
    for (int f = 0; f < 40; f++) {
        float a = W[O_BE1 + f];
#pragma unroll
        for (int p = 0; p < 50; p++) a += W[O_WE1 + f * 50 + p] * v0[p];
        o[f] = leaky(a);
    }
    float4* ot = (float4*)(t1 + (size_t)i * 40);
#pragma unroll
    for (int p = 0; p < 10; p++) ot[p] = make_float4(o[4 * p], o[4 * p + 1], o[4 * p + 2], o[4 * p + 3]);
}

// e2+e3: reads t1, writes mu -> out[n*50 + i*10], log_var -> out[n*60 + i*10]
__global__ __launch_bounds__(256) void k_e23(const float* __restrict__ t1,
                                             const float* __restrict__ W,
                                             float* __restrict__ out, int n) {
    int i = blockIdx.x * 256 + threadIdx.x;
    if (i >= n) return;
    float v1[40];
    const float4* tr = (const float4*)(t1 + (size_t)i * 40);
#pragma unroll
    for (int p = 0; p < 10; p++) {
        float4 q = tr[p];
        v1[4 * p] = q.x; v1[4 * p + 1] = q.y; v1[4 * p + 2] = q.z; v1[4 * p + 3] = q.w;
    }
    float v2[30];
#pragma unroll
    for (int f = 0; f < 30; f++) {
        float a = W[O_BE2 + f];
#pragma unroll
        for (int p = 0; p < 40; p++) a += W[O_WE2 + f * 40 + p] * v1[p];
        v2[f] = leaky(a);
    }
    float v3[20];  // [mu(10) | log_var(10)]
#pragma unroll
    for (int f = 0; f < 20; f++) {
        float a = W[O_BE3 + f];
#pragma unroll
        for (int p = 0; p < 30; p++) a += W[O_WE3 + f * 30 + p] * v2[p];
        v3[f] = a;
    }
    float2* o_mu = (float2*)(out + (size_t)n * 50 + (size_t)i * 10);
    float2* o_lv = (float2*)(out + (size_t)n * 60 + (size_t)i * 10);
#pragma unroll
    for (int p = 0; p < 5; p++) {
        o_mu[p] = make_float2(v3[2 * p], v3[2 * p + 1]);
        o_lv[p] = make_float2(v3[10 + 2 * p], v3[10 + 2 * p + 1]);
    }
}

// reparam + fc + d1 + d2: reads mu/log_var from out, eps; writes z -> out[n*70+i*10],
// d2 activations -> t3[i*40] (reuses h1's region).
__global__ __launch_bounds__(256) void k_zfc(float* outb,  // same buffer read+write, disjoint regions
                                             const void* __restrict__ epsv,
                                             const float* __restrict__ W,
                                             const int* __restrict__ flag,
                                             float* __restrict__ t3, int n) {
    int i = blockIdx.x * 256 + threadIdx.x;
    if (i >= n) return;
    bool isf = flag[0] > 64;
    float mu[10], lv[10];
    const float2* pm = (const float2*)(outb + (size_t)n * 50 + (size_t)i * 10);
    const float2* pl = (const float2*)(outb + (size_t)n * 60 + (size_t)i * 10);
#pragma unroll
    for (int p = 0; p < 5; p++) {
        float2 a = pm[p]; mu[2 * p] = a.x; mu[2 * p + 1] = a.y;
        float2 b = pl[p]; lv[2 * p] = b.x; lv[2 * p + 1] = b.y;
    }
    float ev[10];
    if (isf) {
        const float* p = (const float*)epsv + (size_t)i * 10;
#pragma unroll
        for (int k = 0; k < 10; k++) ev[k] = p[k];
    } else {
        const unsigned short* p = (const unsigned short*)epsv + (size_t)i * 10;
#pragma unroll
        for (int k = 0; k < 10; k++) ev[k] = bf2f(p[k]);
    }
    float z1[10];
#pragma unroll
    for (int k = 0; k < 10; k++) z1[k] = mu[k] + ev[k] * expf(0.5f * lv[k]);
    float z[10];
#pragma unroll
    for (int f = 0; f < 10; f++) {
        float a = W[O_BFC + f];
#pragma unroll
        for (int p = 0; p < 10; p++) a += W[O_WFC + f * 10 + p] * z1[p];
        z[f] = (a > 0.f) ? a : 0.f;
    }
    float2* o_z = (float2*)(outb + (size_t)n * 70 + (size_t)i * 10);
#pragma unroll
    for (int p = 0; p < 5; p++) o_z[p] = make_float2(z[2 * p], z[2 * p + 1]);
    float d1[20];
#pragma unroll
    for (int f = 0; f < 20; f++) {
        float a = W[O_BD1 + f];
#pragma unroll
        for (int p = 0; p < 10; p++) a += W[O_WD1 + f * 10 + p] * z[p];
        d1[f] = leaky(a);
    }
    float d2[40];
#pragma unroll
    for (int f = 0; f < 40; f++) {
        float a = W[O_BD2 + f];
#pragma unroll
        for (int p = 0; p < 20; p++) a += W[O_WD2 + f * 20 + p] * d1[p];
        d2[f] = leaky(a);
    }
    float4* ot = (float4*)(t3 + (size_t)i * 40);
#pragma unroll
    for (int p = 0; p < 10; p++)
        ot[p] = make_float4(d2[4 * p], d2[4 * p + 1], d2[4 * p + 2], d2[4 * p + 3]);
}

// d3 + sigmoid: reads t3, writes mu_prime -> out[i*50]
__global__ __launch_bounds__(256) void k_d3(const float* __restrict__ t3,
                                            const float* __restrict__ W,
                                            float* __restrict__ out, int n) {
    int i = blockIdx.x * 256 + threadIdx.x;
    if (i >= n) return;
    float d2[40];
    const float4* tr = (const float4*)(t3 + (size_t)i * 40);
#pragma unroll
    for (int p = 0; p < 10; p++) {
        float4 q = tr[p];
        d2[4 * p] = q.x; d2[4 * p + 1] = q.y; d2[4 * p + 2] = q.z; d2[4 * p + 3] = q.w;
    }
    float o[50];
#pragma unroll
    for (int f = 0; f < 50; f++) {
        float a = W[O_BD3 + f];
#pragma unroll
        for (int p = 0; p < 40; p++) a += W[O_WD3 + f * 40 + p] * d2[p];
        o[f] = 1.f / (1.f + expf(-a));
    }
    float2* om = (float2*)(out + (size_t)i * 50);
#pragma unroll
    for (int p = 0; p < 25; p++) om[p] = make_float2(o[2 * p], o[2 * p + 1]);
}

extern "C" void kernel_launch(void* const* d_in, const int* in_sizes, int n_in,
                              void* d_out, int out_size, void* d_ws, size_t ws_size,
                              hipStream_t stream) {
    const int N = in_sizes[0] / 150;
    const int E = in_sizes[1] / 2;

    char* w = (char*)d_ws;
    auto alloc = [&](size_t bytes) {
        void* p = (void*)w;
        w += (bytes + 255) & ~(size_t)255;
        return p;
    };
    int* indeg = (int*)alloc((size_t)N * 4);
    int* flag = (int*)alloc(256);
    int* meta = (int*)alloc((size_t)META_INTS * 4);
    float* dinv = (float*)alloc((size_t)N * 4);
    float* Wall = (float*)alloc((size_t)W_TOT * 4);
    int2* spill = (int2*)alloc((size_t)SPILL_CAP * 8);
    float* g = (float*)alloc((size_t)N * GS * 4);
    float* h1 = (float*)alloc((size_t)N * 50 * 4);
    int* ebuf = (int*)alloc((size_t)N * ELLS * 4);

    // bucket (E int2) overlays g [+h1 if needed]: both are written only after
    // k_build2 has consumed the buckets. Fallback to fresh alloc if too small.
    int2* bucket;
    if ((size_t)E * 8 <= (size_t)N * GS * 4 + (size_t)N * 50 * 4) {
        bucket = (int2*)g;
    } else {
        bucket = (int2*)alloc((size_t)E * 8);
    }

    // intermediate reuse: t1 (N*40) in g's region (g dead after k_spill);
    // t3 (N*40) in h1's region (h1 dead after k_e1).
    float* t1 = g;
    float* t3 = h1;

    CW cw;
    static const int wn[16] = {2500, 50, 2000, 40, 1200, 30, 600, 20,
                               100, 10, 200, 20, 800, 40, 2000, 50};
    static const int wo[16] = {O_WG, O_BG, O_WE1, O_BE1, O_WE2, O_BE2, O_WE3, O_BE3,
                               O_WFC, O_BFC, O_WD1, O_BD1, O_WD2, O_BD2, O_WD3, O_BD3};
    for (int k = 0; k < 16; k++) {
        cw.src[k] = d_in[3 + k];
        cw.off[k] = wo[k];
        cw.n[k] = wn[k];
    }

    int nbN = (N + 255) / 256;

    k_zero<<<nbN, 256, 0, stream>>>(indeg, flag, meta, N);
    k_detect<<<512, 256, 0, stream>>>((const unsigned*)d_in[0], (long)N * 75,
                                      (const unsigned*)d_in[1], (long)E, flag);
    k_hist<<<1024, 256, 0, stream>>>((const int*)d_in[1], flag, meta, E, N);
    k_scan<<<1, 64, 0, stream>>>(meta);
    k_part<<<2048, 256, 0, stream>>>((const int*)d_in[1], flag, meta, bucket, E, N);
    k_build2<<<4096, 256, 0, stream>>>(bucket, meta, indeg, ebuf, spill, flag, N, 0);
    k_build2<<<4096, 256, 0, stream>>>(bucket, meta, indeg, ebuf, spill, flag, N, 1);
    k_dinv<<<nbN, 256, 0, stream>>>(indeg, dinv, N);
    k_convw<<<16, 256, 0, stream>>>(cw, Wall, flag);
    k_g<<<nbN, 256, 0, stream>>>(d_in[0], Wall, dinv, flag, g, N);
    k_gather<<<(N + 3) / 4, 256, 0, stream>>>(g, indeg, ebuf, dinv, Wall, h1, N);
    k_spill<<<64, 256, 0, stream>>>(spill, flag, g, dinv, h1);
    k_e1<<<nbN, 256, 0, stream>>>(h1, Wall, t1, N);
    k_e23<<<nbN, 256, 0, stream>>>(t1, Wall, (float*)d_out, N);
    k_zfc<<<nbN, 256, 0, stream>>>((float*)d_out, d_in[2], Wall, flag, t3, N);
    k_d3<<<nbN, 256, 0, stream>>>(t3, Wall, (float*)d_out, N);
}

// Round 5
// 1083.484 us; speedup vs baseline: 1.0027x; 1.0027x over previous
//
#include <hip/hip_runtime.h>

// GCN-VAE forward, fp32 pipeline, dtype-adaptive inputs, fp32 outputs.
// flag[0] = bf16-view NaN patterns in x sample   (>64        -> float inputs are fp32)
// flag[1] = zero hi-words in edge-pair sample    (>DET_ES/2  -> edge_index is int64)
// flag[2] = overflow-edge count (ELL slots exceeded; handled by k_spill)
// Round 7: counting-sort edge partition (hist/scan/part) + per-XCD ELL build.
// Round 8: k_gather was issue-bound (33% VALU, 48% HBM, 8 dword loads + 8 shfl
// per 8 edges). Now 4 edges/instruction: lane=(q,r), one float4 load per lane
// gathers 4 full 256B rows per instruction; XOR-reduce across q groups at end.
// g pad floats 50..63 zeroed in k_g; h1 re-strided to 56 floats (16B-aligned).

#define NEG 0.01f
#define GS 64        // g row stride (floats) -> 256B rows
#define HS 56        // h1 row stride (floats) -> 224B rows, 16B aligned
#define ELLS 64      // ELL slots per node
#define NB 16        // partition buckets == dst slices
#define SPILL_CAP 65536

// detect sampling: 1024 chunks x 1024 words/pairs per side
#define DET_ES (1024 * 1024)
#define IS64_THRESH (DET_ES / 2)

// meta layout (ints): [k*16] bcount_k (padded) | [256+k] boffs_k | [288+k] bend_k |
// [512+k*16] gptr_k (padded write pointers)
#define META_INTS 1024

typedef int vint2 __attribute__((ext_vector_type(2)));

static __device__ __forceinline__ float bf2f(unsigned short u) {
    return __uint_as_float(((unsigned)u) << 16);
}
static __device__ __forceinline__ float leaky(float a) { return (a >= 0.f) ? a : NEG * a; }

__global__ void k_zero(int* __restrict__ indeg, int* __restrict__ flag,
                       int* __restrict__ meta, int n) {
    int i = blockIdx.x * 256 + threadIdx.x;
    if (i < n) indeg[i] = 0;
    if (blockIdx.x == 0) {
        for (int j = threadIdx.x; j < META_INTS; j += 256) meta[j] = 0;
        if (threadIdx.x == 0) { flag[0] = 0; flag[1] = 0; flag[2] = 0; }
    }
}

// Sampled dtype detection. waves 0..1023 sample x words, 1024..2047 edge hi-words.
__global__ void k_detect(const unsigned* __restrict__ x, long xwords,
                         const unsigned* __restrict__ ei, long epairs,
                         int* __restrict__ flag) {
    int gw = (blockIdx.x * 256 + threadIdx.x) >> 6;  // 0..2047
    int lane = threadIdx.x & 63;
    int side = gw >> 10;
    int ch = gw & 1023;
    int c = 0;
    if (side == 0) {
        long step = xwords >> 10;
        long base = (long)ch * step;
        if (base + 1024 > xwords) base = xwords > 1024 ? xwords - 1024 : 0;
#pragma unroll
        for (int t = 0; t < 16; t++) {
            long idx = base + t * 64 + lane;
            if (idx < xwords) {
                unsigned w = x[idx];
                if (((w >> 23) & 0xFFu) == 0xFFu || ((w >> 7) & 0xFFu) == 0xFFu) c++;
            }
        }
        for (int k = 32; k; k >>= 1) c += __shfl_xor(c, k);
        if (lane == 0 && c) atomicAdd(&flag[0], c);
    } else {
        long step = epairs >> 10;
        long base = (long)ch * step;
        if (base + 1024 > epairs) base = epairs > 1024 ? epairs - 1024 : 0;
#pragma unroll
        for (int t = 0; t < 16; t++) {
            long idx = base + t * 64 + lane;
            if (idx < epairs && ei[2 * idx + 1] == 0u) c++;
        }
        for (int k = 32; k; k >>= 1) c += __shfl_xor(c, k);
        if (lane == 0 && c) atomicAdd(&flag[1], c);
    }
}

// Exact per-bucket histogram of dst (one pass, LDS-aggregated).
__global__ __launch_bounds__(256) void k_hist(const int* __restrict__ ei,
                                              const int* __restrict__ flag,
                                              int* __restrict__ meta, int E, int N) {
    __shared__ int lh[NB];
    if (threadIdx.x < NB) lh[threadIdx.x] = 0;
    __syncthreads();
    bool is64 = flag[1] > IS64_THRESH;
    unsigned usw = ((unsigned)N + NB - 1) / NB;
    const long stride = 1024L * 256;
    if (is64) {
        const int2* p = (const int2*)ei;
        for (long e = (long)blockIdx.x * 256 + threadIdx.x; e < E; e += stride) {
            int d = p[E + e].x;
            if ((unsigned)d < (unsigned)N) atomicAdd(&lh[(unsigned)d / usw], 1);
        }
    } else {
        for (long e = (long)blockIdx.x * 256 + threadIdx.x; e < E; e += stride) {
            int d = ei[E + e];
            if ((unsigned)d < (unsigned)N) atomicAdd(&lh[(unsigned)d / usw], 1);
        }
    }
    __syncthreads();
    if (threadIdx.x < NB && lh[threadIdx.x]) atomicAdd(&meta[threadIdx.x * 16], lh[threadIdx.x]);
}

// 16-element prefix sum -> bucket offsets + write pointers.
__global__ void k_scan(int* __restrict__ meta) {
    if (threadIdx.x == 0) {
        int acc = 0;
        for (int k = 0; k < NB; k++) {
            int c = meta[k * 16];
            meta[256 + k] = acc;        // boffs
            meta[512 + k * 16] = acc;   // gptr
            acc += c;
            meta[288 + k] = acc;        // bend
        }
    }
}

// Single-pass partition of edges into NB dst-range buckets.
// LDS staging: 16 buckets x 512 int2 (64KB); flush 256-entry (2KB) coalesced
// chunks claimed by one global atomic each.
__global__ __launch_bounds__(256) void k_part(const int* __restrict__ ei,
                                              const int* __restrict__ flag,
                                              int* __restrict__ meta,
                                              int2* __restrict__ bucket, int E, int N) {
    __shared__ int2 buf[NB][512];
    __shared__ int lcnt[NB];
    __shared__ int lbase;
    if (threadIdx.x < NB) lcnt[threadIdx.x] = 0;
    __syncthreads();
    bool is64 = flag[1] > IS64_THRESH;
    unsigned usw = ((unsigned)N + NB - 1) / NB;
    int nsteps = (E + 2048 * 256 - 1) / (2048 * 256);
    for (int step = 0; step < nsteps; step++) {
        long e = (long)(step * 2048 + blockIdx.x) * 256 + threadIdx.x;
        int b = -1;
        int2 sd;
        if (e < E) {
            int src, d;
            if (is64) {
                const int2* p = (const int2*)ei;
                src = p[e].x;
                d = p[E + e].x;
            } else {
                src = ei[e];
                d = ei[E + e];
            }
            if ((unsigned)d < (unsigned)N) {
                b = (int)((unsigned)d / usw);
                sd = make_int2(src, d);
            }
        }
        if (b >= 0) {
            int p = atomicAdd(&lcnt[b], 1);  // max 255 remainder + 256 pushes = 511 < 512
            buf[b][p] = sd;
        }
        __syncthreads();
        for (int k = 0; k < NB; k++) {
            int cnt = lcnt[k];  // uniform (post-barrier)
            if (cnt >= 256) {
                if (threadIdx.x == 0) lbase = atomicAdd(&meta[512 + k * 16], 256);
                __syncthreads();
                bucket[lbase + threadIdx.x] = buf[k][threadIdx.x];
                int rem = cnt - 256;
                int2 r;
                if (threadIdx.x < rem) r = buf[k][256 + threadIdx.x];
                __syncthreads();
                if (threadIdx.x < rem) buf[k][threadIdx.x] = r;
                if (threadIdx.x == 0) lcnt[k] = rem;
                __syncthreads();
            }
        }
    }
    // drain remainders (<256 each)
    for (int k = 0; k < NB; k++) {
        int cnt = lcnt[k];
        if (cnt > 0) {
            if (threadIdx.x == 0) lbase = atomicAdd(&meta[512 + k * 16], cnt);
            __syncthreads();
            if (threadIdx.x < cnt) bucket[lbase + threadIdx.x] = buf[k][threadIdx.x];
            __syncthreads();
        }
    }
}

// ELL build from buckets. One launch per pass; pass p handles slices p*8..p*8+7,
// slice s on XCD (s&7) via blockIdx%8 round-robin: 3.2MB ELL window + 50KB indeg
// stays L2-resident. Bucket stream is truly read-once -> non-temporal.
__global__ __launch_bounds__(256) void k_build2(const int2* __restrict__ bucket,
                                                const int* __restrict__ meta,
                                                int* __restrict__ indeg,
                                                int* __restrict__ ebuf,
                                                int2* __restrict__ spill,
                                                int* __restrict__ flag, int N, int pass) {
    int s = pass * 8 + (blockIdx.x & 7);
    int q = blockIdx.x >> 3;  // 0..511
    int lo = meta[256 + s];
    int hi = meta[288 + s];
    for (int idx = lo + q * 256 + threadIdx.x; idx < hi; idx += 512 * 256) {
        vint2 t = __builtin_nontemporal_load((const vint2*)&bucket[idx]);
        int src = t.x;
        int d = t.y;
        if ((unsigned)src >= (unsigned)N) continue;
        int c = atomicAdd(&indeg[d], 1);
        if (c < ELLS) {
            ebuf[(size_t)d * ELLS + c] = src;
        } else {
            int o = atomicAdd(&flag[2], 1);
            if (o < SPILL_CAP) spill[o] = make_int2(src, d);
        }
    }
}

__global__ void k_dinv(const int* __restrict__ indeg, float* __restrict__ dinv, int n) {
    int i = blockIdx.x * 256 + threadIdx.x;
    if (i < n) dinv[i] = rsqrtf(1.0f + (float)indeg[i]);  // deg includes self loop
}

// convert the 16 weight/bias arrays into one fp32 block; block b handles array b.
struct CW {
    const void* src[16];
    int off[16];
    int n[16];
};
__global__ void k_convw(CW cw, float* __restrict__ dst, const int* __restrict__ flag) {
    int b = blockIdx.x;
    bool isf = flag[0] > 64;
    const float* sf = (const float*)cw.src[b];
    const unsigned short* sh = (const unsigned short*)cw.src[b];
    float* d = dst + cw.off[b];
    int n = cw.n[b];
    for (int i = threadIdx.x; i < n; i += 256) d[i] = isf ? sf[i] : bf2f(sh[i]);
}

// weight-block offsets (floats)
#define O_WG 0
#define O_BG 2500
#define O_WE1 2550
#define O_BE1 4550
#define O_WE2 4590
#define O_BE2 5790
#define O_WE3 5820
#define O_BE3 6420
#define O_WFC 6440
#define O_BFC 6540
#define O_WD1 6550
#define O_BD1 6750
#define O_WD2 6770
#define O_BD2 7570
#define O_WD3 7610
#define O_BD3 9610
#define W_TOT 9660

// g[i] = (x[i,100:150] @ Wg.T) * dinv[i]  -> fp32, stride GS; pad 50..63 zeroed.
__global__ __launch_bounds__(256) void k_g(const void* __restrict__ xv,
                                           const float* __restrict__ W,
                                           const float* __restrict__ dinv,
                                           const int* __restrict__ flag,
                                           float* __restrict__ g, int n) {
    int i = blockIdx.x * 256 + threadIdx.x;
    if (i >= n) return;
    bool isf = flag[0] > 64;
    float xr[50];
    if (isf) {
        // byte offset (i*150+100)*4 = 600i+400 -> 8B aligned: float2 loads
        const float2* p = (const float2*)((const float*)xv + (size_t)i * 150 + 100);
#pragma unroll
        for (int k = 0; k < 25; k++) {
            float2 q = p[k];
            xr[2 * k] = q.x;
            xr[2 * k + 1] = q.y;
        }
    } else {
        // byte offset (i*150+100)*2 = 300i+200 -> 4B aligned: uint loads (2 bf16)
        const unsigned* p = (const unsigned*)((const unsigned short*)xv + (size_t)i * 150 + 100);
#pragma unroll
        for (int k = 0; k < 25; k++) {
            unsigned u = p[k];
            xr[2 * k] = __uint_as_float(u << 16);
            xr[2 * k + 1] = __uint_as_float(u & 0xFFFF0000u);
        }
    }
    const float* Wg = W + O_WG;
    float di = dinv[i];
    float o[64];
#pragma unroll
    for (int f = 0; f < 50; f += 2) {
        float a0 = 0.f, a1 = 0.f;
#pragma unroll
        for (int p = 0; p < 50; p++) {
            a0 += Wg[f * 50 + p] * xr[p];
            a1 += Wg[(f + 1) * 50 + p] * xr[p];
        }
        o[f] = a0 * di;
        o[f + 1] = a1 * di;
    }
#pragma unroll
    for (int f = 50; f < 64; f++) o[f] = 0.f;
    float4* gr4 = (float4*)(g + (size_t)i * GS);
#pragma unroll
    for (int p = 0; p < 16; p++)
        gr4[p] = make_float4(o[4 * p], o[4 * p + 1], o[4 * p + 2], o[4 * p + 3]);
}

// wave per node, 4 edges per instruction: lane=(q,r), q=lane>>4 picks edge slot,
// r=lane&15 picks float4 within the 256B row. One dwordx4 gathers 4 full rows.
// 4 accumulators = 16 edges in flight; XOR-reduce over q at the end.
__global__ __launch_bounds__(256) void k_gather(const float* __restrict__ g,
                                                const int* __restrict__ indeg,
                                                const int* __restrict__ ebuf,
                                                const float* __restrict__ dinv,
                                                const float* __restrict__ W,
                                                float* __restrict__ h1, int n) {
    int wid = threadIdx.x >> 6;
    int lane = threadIdx.x & 63;
    int i = blockIdx.x * 4 + wid;
    if (i >= n) return;
    int q = lane >> 4;
    int r = lane & 15;
    int cnt = indeg[i];
    if (cnt > ELLS) cnt = ELLS;
    int ev = (lane < cnt) ? ebuf[(size_t)i * ELLS + lane] : 0;
    const float4* g4 = (const float4*)g;
    float4 a0 = make_float4(0.f, 0.f, 0.f, 0.f);
    float4 a1 = a0, a2 = a0, a3 = a0;
    int m = 0;
    for (; m + 16 <= cnt; m += 16) {
        int j0 = __shfl(ev, m + q);
        int j1 = __shfl(ev, m + 4 + q);
        int j2 = __shfl(ev, m + 8 + q);
        int j3 = __shfl(ev, m + 12 + q);
        float4 t0 = g4[(size_t)j0 * 16 + r];
        float4 t1 = g4[(size_t)j1 * 16 + r];
        float4 t2 = g4[(size_t)j2 * 16 + r];
        float4 t3 = g4[(size_t)j3 * 16 + r];
        a0.x += t0.x; a0.y += t0.y; a0.z += t0.z; a0.w += t0.w;
        a1.x += t1.x; a1.y += t1.y; a1.z += t1.z; a1.w += t1.w;
        a2.x += t2.x; a2.y += t2.y; a2.z += t2.z; a2.w += t2.w;
        a3.x += t3.x; a3.y += t3.y; a3.z += t3.z; a3.w += t3.w;
    }
    for (; m + 4 <= cnt; m += 4) {
        int j = __shfl(ev, m + q);
        float4 t = g4[(size_t)j * 16 + r];
        a0.x += t.x; a0.y += t.y; a0.z += t.z; a0.w += t.w;
    }
    if (m < cnt) {
        int j = __shfl(ev, m + q);  // m+q <= 63 always here (cnt<=64, tail only when cnt%4!=0)
        if (m + q < cnt) {
            float4 t = g4[(size_t)j * 16 + r];
            a0.x += t.x; a0.y += t.y; a0.z += t.z; a0.w += t.w;
        }
    }
    float4 s;
    s.x = (a0.x + a1.x) + (a2.x + a3.x);
    s.y = (a0.y + a1.y) + (a2.y + a3.y);
    s.z = (a0.z + a1.z) + (a2.z + a3.z);
    s.w = (a0.w + a1.w) + (a2.w + a3.w);
    s.x += __shfl_xor(s.x, 16); s.y += __shfl_xor(s.y, 16);
    s.z += __shfl_xor(s.z, 16); s.w += __shfl_xor(s.w, 16);
    s.x += __shfl_xor(s.x, 32); s.y += __shfl_xor(s.y, 32);
    s.z += __shfl_xor(s.z, 32); s.w += __shfl_xor(s.w, 32);
    if (lane < 16) {
        float di = dinv[i];
        float4 self = g4[(size_t)i * 16 + lane];
        float4 b = ((const float4*)(W + O_BG))[lane];  // O_BG*4=10000B, 16B aligned
        float4 h;
        h.x = (s.x + self.x) * di + b.x;
        h.y = (s.y + self.y) * di + b.y;
        h.z = (s.z + self.z) * di + b.z;
        h.w = (s.w + self.w) * di + b.w;
        float* hr = h1 + (size_t)i * HS;
        if (lane < 12) {
            ((float4*)hr)[lane] = h;  // 224B rows: 16B aligned
        } else if (lane == 12) {
            hr[48] = h.x;
            hr[49] = h.y;
        }
    }
}

// overflow edges (deg > ELLS): atomic-add their contribution into h1.
__global__ void k_spill(const int2* __restrict__ spill, const int* __restrict__ flag,
                        const float* __restrict__ g, const float* __restrict__ dinv,
                        float* __restrict__ h1) {
    int nov = flag[2];
    if (nov > SPILL_CAP) nov = SPILL_CAP;
    int lane = threadIdx.x & 63;
    int wave = (blockIdx.x * 256 + threadIdx.x) >> 6;
    for (int e = wave; e < nov; e += gridDim.x * 4) {
        int2 sd = spill[e];
        if (lane < 50)
            atomicAdd(&h1[(size_t)sd.y * HS + lane], g[(size_t)sd.x * GS + lane] * dinv[sd.y]);
    }
}

// ---- MLP split: each kernel has <16KB code and <8KB scalar weight stream ----

// e1: t1[i,0:40] = leaky(h1[i,:] @ We1.T + be1)
__global__ __launch_bounds__(256) void k_e1(const float* __restrict__ h1,
                                            const float* __restrict__ W,
                                            float* __restrict__ t1, int n) {
    int i = blockIdx.x * 256 + threadIdx.x;
    if (i >= n) return;
    float v0[50];
    const float* hr = h1 + (size_t)i * HS;
    const float4* hr4 = (const float4*)hr;
#pragma unroll
    for (int p = 0; p < 12; p++) {
        float4 t = hr4[p];
        v0[4 * p] = t.x; v0[4 * p + 1] = t.y; v0[4 * p + 2] = t.z; v0[4 * p + 3] = t.w;
    }
    v0[48] = hr[48];
    v0[49] = hr[49];
    float o[40];
#pragma unroll
    for (int f = 0; f < 40; f++) {
        float a = W[O_BE1 + f];
#pragma unroll
        for (int p = 0; p < 50; p++) a += W[O_WE1 + f * 50 + p] * v0[p];
        o[f] = leaky(a);
    }
    float4* ot = (float4*)(t1 + (size_t)i * 40);
#pragma unroll
    for (int p = 0; p < 10; p++) ot[p] = make_float4(o[4 * p], o[4 * p + 1], o[4 * p + 2], o[4 * p + 3]);
}

// e2+e3: reads t1, writes mu -> out[n*50 + i*10], log_var -> out[n*60 + i*10]
__global__ __launch_bounds__(256) void k_e23(const float* __restrict__ t1,
                                             const float* __restrict__ W,
                                             float* __restrict__ out, int n) {
    int i = blockIdx.x * 256 + threadIdx.x;
    if (i >= n) return;
    float v1[40];
    const float4* tr = (const float4*)(t1 + (size_t)i * 40);
#pragma unroll
    for (int p = 0; p < 10; p++) {
        float4 q = tr[p];
        v1[4 * p] = q.x; v1[4 * p + 1] = q.y; v1[4 * p + 2] = q.z; v1[4 * p + 3] = q.w;
    }
    float v2[30];
#pragma unroll
    for (int f = 0; f < 30; f++) {
        float a = W[O_BE2 + f];
#pragma unroll
        for (int p = 0; p < 40; p++) a += W[O_WE2 + f * 40 + p] * v1[p];
        v2[f] = leaky(a);
    }
    float v3[20];  // [mu(10) | log_var(10)]
#pragma unroll
    for (int f = 0; f < 20; f++) {
        float a = W[O_BE3 + f];
#pragma unroll
        for (int p = 0; p < 30; p++) a += W[O_WE3 + f * 30 + p] * v2[p];
        v3[f] = a;
    }
    float2* o_mu = (float2*)(out + (size_t)n * 50 + (size_t)i * 10);
    float2* o_lv = (float2*)(out + (size_t)n * 60 + (size_t)i * 10);
#pragma unroll
    for (int p = 0; p < 5; p++) {
        o_mu[p] = make_float2(v3[2 * p], v3[2 * p + 1]);
        o_lv[p] = make_float2(v3[10 + 2 * p], v3[10 + 2 * p + 1]);
    }
}

// reparam + fc + d1 + d2: reads mu/log_var from out, eps; writes z -> out[n*70+i*10],
// d2 activations -> t3[i*40] (reuses h1's region).
__global__ __launch_bounds__(256) void k_zfc(float* outb,  // same buffer read+write, disjoint regions
                                             const void* __restrict__ epsv,
                                             const float* __restrict__ W,
                                             const int* __restrict__ flag,
                                             float* __restrict__ t3, int n) {
    int i = blockIdx.x * 256 + threadIdx.x;
    if (i >= n) return;
    bool isf = flag[0] > 64;
    float mu[10], lv[10];
    const float2* pm = (const float2*)(outb + (size_t)n * 50 + (size_t)i * 10);
    const float2* pl = (const float2*)(outb + (size_t)n * 60 + (size_t)i * 10);
#pragma unroll
    for (int p = 0; p < 5; p++) {
        float2 a = pm[p]; mu[2 * p] = a.x; mu[2 * p + 1] = a.y;
        float2 b = pl[p]; lv[2 * p] = b.x; lv[2 * p + 1] = b.y;
    }
    float ev[10];
    if (isf) {
        const float* p = (const float*)epsv + (size_t)i * 10;
#pragma unroll
        for (int k = 0; k < 10; k++) ev[k] = p[k];
    } else {
        const unsigned short* p = (const unsigned short*)epsv + (size_t)i * 10;
#pragma unroll
        for (int k = 0; k < 10; k++) ev[k] = bf2f(p[k]);
    }
    float z1[10];
#pragma unroll
    for (int k = 0; k < 10; k++) z1[k] = mu[k] + ev[k] * expf(0.5f * lv[k]);
    float z[10];
#pragma unroll
    for (int f = 0; f < 10; f++) {
        float a = W[O_BFC + f];
#pragma unroll
        for (int p = 0; p < 10; p++) a += W[O_WFC + f * 10 + p] * z1[p];
        z[f] = (a > 0.f) ? a : 0.f;
    }
    float2* o_z = (float2*)(outb + (size_t)n * 70 + (size_t)i * 10);
#pragma unroll
    for (int p = 0; p < 5; p++) o_z[p] = make_float2(z[2 * p], z[2 * p + 1]);
    float d1[20];
#pragma unroll
    for (int f = 0; f < 20; f++) {
        float a = W[O_BD1 + f];
#pragma unroll
        for (int p = 0; p < 10; p++) a += W[O_WD1 + f * 10 + p] * z[p];
        d1[f] = leaky(a);
    }
    float d2[40];
#pragma unroll
    for (int f = 0; f < 40; f++) {
        float a = W[O_BD2 + f];
#pragma unroll
        for (int p = 0; p < 20; p++) a += W[O_WD2 + f * 20 + p] * d1[p];
        d2[f] = leaky(a);
    }
    float4* ot = (float4*)(t3 + (size_t)i * 40);
#pragma unroll
    for (int p = 0; p < 10; p++)
        ot[p] = make_float4(d2[4 * p], d2[4 * p + 1], d2[4 * p + 2], d2[4 * p + 3]);
}

// d3 + sigmoid: reads t3, writes mu_prime -> out[i*50]
__global__ __launch_bounds__(256) void k_d3(const float* __restrict__ t3,
                                            const float* __restrict__ W,
                                            float* __restrict__ out, int n) {
    int i = blockIdx.x * 256 + threadIdx.x;
    if (i >= n) return;
    float d2[40];
    const float4* tr = (const float4*)(t3 + (size_t)i * 40);
#pragma unroll
    for (int p = 0; p < 10; p++) {
        float4 q = tr[p];
        d2[4 * p] = q.x; d2[4 * p + 1] = q.y; d2[4 * p + 2] = q.z; d2[4 * p + 3] = q.w;
    }
    float o[50];
#pragma unroll
    for (int f = 0; f < 50; f++) {
        float a = W[O_BD3 + f];
#pragma unroll
        for (int p = 0; p < 40; p++) a += W[O_WD3 + f * 40 + p] * d2[p];
        o[f] = 1.f / (1.f + expf(-a));
    }
    float2* om = (float2*)(out + (size_t)i * 50);
#pragma unroll
    for (int p = 0; p < 25; p++) om[p] = make_float2(o[2 * p], o[2 * p + 1]);
}

extern "C" void kernel_launch(void* const* d_in, const int* in_sizes, int n_in,
                              void* d_out, int out_size, void* d_ws, size_t ws_size,
                              hipStream_t stream) {
    const int N = in_sizes[0] / 150;
    const int E = in_sizes[1] / 2;

    char* w = (char*)d_ws;
    auto alloc = [&](size_t bytes) {
        void* p = (void*)w;
        w += (bytes + 255) & ~(size_t)255;
        return p;
    };
    int* indeg = (int*)alloc((size_t)N * 4);
    int* flag = (int*)alloc(256);
    int* meta = (int*)alloc((size_t)META_INTS * 4);
    float* dinv = (float*)alloc((size_t)N * 4);
    float* Wall = (float*)alloc((size_t)W_TOT * 4);
    int2* spill = (int2*)alloc((size_t)SPILL_CAP * 8);
    float* g = (float*)alloc((size_t)N * GS * 4);
    float* h1 = (float*)alloc((size_t)N * HS * 4);
    int* ebuf = (int*)alloc((size_t)N * ELLS * 4);

    // bucket (E int2) overlays g [+h1 if needed]: both are written only after
    // k_build2 has consumed the buckets. Fallback to fresh alloc if too small.
    int2* bucket;
    if ((size_t)E * 8 <= (size_t)N * GS * 4 + (size_t)N * HS * 4) {
        bucket = (int2*)g;
    } else {
        bucket = (int2*)alloc((size_t)E * 8);
    }

    // intermediate reuse: t1 (N*40) in g's region (g dead after k_spill);
    // t3 (N*40) in h1's region (h1 dead after k_e1).
    float* t1 = g;
    float* t3 = h1;

    CW cw;
    static const int wn[16] = {2500, 50, 2000, 40, 1200, 30, 600, 20,
                               100, 10, 200, 20, 800, 40, 2000, 50};
    static const int wo[16] = {O_WG, O_BG, O_WE1, O_BE1, O_WE2, O_BE2, O_WE3, O_BE3,
                               O_WFC, O_BFC, O_WD1, O_BD1, O_WD2, O_BD2, O_WD3, O_BD3};
    for (int k = 0; k < 16; k++) {
        cw.src[k] = d_in[3 + k];
        cw.off[k] = wo[k];
        cw.n[k] = wn[k];
    }

    int nbN = (N + 255) / 256;

    k_zero<<<nbN, 256, 0, stream>>>(indeg, flag, meta, N);
    k_detect<<<512, 256, 0, stream>>>((const unsigned*)d_in[0], (long)N * 75,
                                      (const unsigned*)d_in[1], (long)E, flag);
    k_hist<<<1024, 256, 0, stream>>>((const int*)d_in[1], flag, meta, E, N);
    k_scan<<<1, 64, 0, stream>>>(meta);
    k_part<<<2048, 256, 0, stream>>>((const int*)d_in[1], flag, meta, bucket, E, N);
    k_build2<<<4096, 256, 0, stream>>>(bucket, meta, indeg, ebuf, spill, flag, N, 0);
    k_build2<<<4096, 256, 0, stream>>>(bucket, meta, indeg, ebuf, spill, flag, N, 1);
    k_dinv<<<nbN, 256, 0, stream>>>(indeg, dinv, N);
    k_convw<<<16, 256, 0, stream>>>(cw, Wall, flag);
    k_g<<<nbN, 256, 0, stream>>>(d_in[0], Wall, dinv, flag, g, N);
    k_gather<<<(N + 3) / 4, 256, 0, stream>>>(g, indeg, ebuf, dinv, Wall, h1, N);
    k_spill<<<64, 256, 0, stream>>>(spill, flag, g, dinv, h1);
    k_e1<<<nbN, 256, 0, stream>>>(h1, Wall, t1, N);
    k_e23<<<nbN, 256, 0, stream>>>(t1, Wall, (float*)d_out, N);
    k_zfc<<<nbN, 256, 0, stream>>>((float*)d_out, d_in[2], Wall, flag, t3, N);
    k_d3<<<nbN, 256, 0, stream>>>(t3, Wall, (float*)d_out, N);
}

// Round 6
// 980.607 us; speedup vs baseline: 1.1079x; 1.1049x over previous
//
#include <hip/hip_runtime.h>

// GCN-VAE forward, fp32 pipeline, dtype-adaptive inputs, fp32 outputs.
// flag[0] = bf16-view NaN patterns in x sample   (>64        -> float inputs are fp32)
// flag[1] = zero hi-words in edge-pair sample    (>DET_ES/2  -> edge_index is int64)
// flag[2] = overflow-edge count (ELL slots exceeded; handled by k_spill)
// Round 7: counting-sort edge partition (hist/scan/part) + per-XCD ELL build.
// Round 8: k_gather 4 edges/instruction (float4 lanes, XOR-reduce). Result: VALU
// 33->24% but dur flat, FETCH flat 786MB -> k_gather is L2-miss-traffic bound
// (random 256B rows from 51.2MB array vs 4MB/XCD L2; 15x miss amplification).
// Round 9: g stored as fp16 (compute fp32, convert in k_g): row 256B -> 128B,
// halves per-edge miss traffic. t1 moved to ebuf region (g region shrank).

#define NEG 0.01f
#define GS 64        // g row stride in HALVES -> 128B rows (2 granules)
#define HS 56        // h1 row stride (floats) -> 224B rows, 16B aligned
#define ELLS 64      // ELL slots per node
#define NB 16        // partition buckets == dst slices
#define SPILL_CAP 65536

// detect sampling: 1024 chunks x 1024 words/pairs per side
#define DET_ES (1024 * 1024)
#define IS64_THRESH (DET_ES / 2)

// meta layout (ints): [k*16] bcount_k (padded) | [256+k] boffs_k | [288+k] bend_k |
// [512+k*16] gptr_k (padded write pointers)
#define META_INTS 1024

typedef int vint2 __attribute__((ext_vector_type(2)));
typedef _Float16 half4v __attribute__((ext_vector_type(4)));
typedef _Float16 half8v __attribute__((ext_vector_type(8)));

static __device__ __forceinline__ float bf2f(unsigned short u) {
    return __uint_as_float(((unsigned)u) << 16);
}
static __device__ __forceinline__ float leaky(float a) { return (a >= 0.f) ? a : NEG * a; }

__global__ void k_zero(int* __restrict__ indeg, int* __restrict__ flag,
                       int* __restrict__ meta, int n) {
    int i = blockIdx.x * 256 + threadIdx.x;
    if (i < n) indeg[i] = 0;
    if (blockIdx.x == 0) {
        for (int j = threadIdx.x; j < META_INTS; j += 256) meta[j] = 0;
        if (threadIdx.x == 0) { flag[0] = 0; flag[1] = 0; flag[2] = 0; }
    }
}

// Sampled dtype detection. waves 0..1023 sample x words, 1024..2047 edge hi-words.
__global__ void k_detect(const unsigned* __restrict__ x, long xwords,
                         const unsigned* __restrict__ ei, long epairs,
                         int* __restrict__ flag) {
    int gw = (blockIdx.x * 256 + threadIdx.x) >> 6;  // 0..2047
    int lane = threadIdx.x & 63;
    int side = gw >> 10;
    int ch = gw & 1023;
    int c = 0;
    if (side == 0) {
        long step = xwords >> 10;
        long base = (long)ch * step;
        if (base + 1024 > xwords) base = xwords > 1024 ? xwords - 1024 : 0;
#pragma unroll
        for (int t = 0; t < 16; t++) {
            long idx = base + t * 64 + lane;
            if (idx < xwords) {
                unsigned w = x[idx];
                if (((w >> 23) & 0xFFu) == 0xFFu || ((w >> 7) & 0xFFu) == 0xFFu) c++;
            }
        }
        for (int k = 32; k; k >>= 1) c += __shfl_xor(c, k);
        if (lane == 0 && c) atomicAdd(&flag[0], c);
    } else {
        long step = epairs >> 10;
        long base = (long)ch * step;
        if (base + 1024 > epairs) base = epairs > 1024 ? epairs - 1024 : 0;
#pragma unroll
        for (int t = 0; t < 16; t++) {
            long idx = base + t * 64 + lane;
            if (idx < epairs && ei[2 * idx + 1] == 0u) c++;
        }
        for (int k = 32; k; k >>= 1) c += __shfl_xor(c, k);
        if (lane == 0 && c) atomicAdd(&flag[1], c);
    }
}

// Exact per-bucket histogram of dst (one pass, LDS-aggregated).
__global__ __launch_bounds__(256) void k_hist(const int* __restrict__ ei,
                                              const int* __restrict__ flag,
                                              int* __restrict__ meta, int E, int N) {
    __shared__ int lh[NB];
    if (threadIdx.x < NB) lh[threadIdx.x] = 0;
    __syncthreads();
    bool is64 = flag[1] > IS64_THRESH;
    unsigned usw = ((unsigned)N + NB - 1) / NB;
    const long stride = 1024L * 256;
    if (is64) {
        const int2* p = (const int2*)ei;
        for (long e = (long)blockIdx.x * 256 + threadIdx.x; e < E; e += stride) {
            int d = p[E + e].x;
            if ((unsigned)d < (unsigned)N) atomicAdd(&lh[(unsigned)d / usw], 1);
        }
    } else {
        for (long e = (long)blockIdx.x * 256 + threadIdx.x; e < E; e += stride) {
            int d = ei[E + e];
            if ((unsigned)d < (unsigned)N) atomicAdd(&lh[(unsigned)d / usw], 1);
        }
    }
    __syncthreads();
    if (threadIdx.x < NB && lh[threadIdx.x]) atomicAdd(&meta[threadIdx.x * 16], lh[threadIdx.x]);
}

// 16-element prefix sum -> bucket offsets + write pointers.
__global__ void k_scan(int* __restrict__ meta) {
    if (threadIdx.x == 0) {
        int acc = 0;
        for (int k = 0; k < NB; k++) {
            int c = meta[k * 16];
            meta[256 + k] = acc;        // boffs
            meta[512 + k * 16] = acc;   // gptr
            acc += c;
            meta[288 + k] = acc;        // bend
        }
    }
}

// Single-pass partition of edges into NB dst-range buckets.
// LDS staging: 16 buckets x 512 int2 (64KB); flush 256-entry (2KB) coalesced
// chunks claimed by one global atomic each.
__global__ __launch_bounds__(256) void k_part(const int* __restrict__ ei,
                                              const int* __restrict__ flag,
                                              int* __restrict__ meta,
                                              int2* __restrict__ bucket, int E, int N) {
    __shared__ int2 buf[NB][512];
    __shared__ int lcnt[NB];
    __shared__ int lbase;
    if (threadIdx.x < NB) lcnt[threadIdx.x] = 0;
    __syncthreads();
    bool is64 = flag[1] > IS64_THRESH;
    unsigned usw = ((unsigned)N + NB - 1) / NB;
    int nsteps = (E + 2048 * 256 - 1) / (2048 * 256);
    for (int step = 0; step < nsteps; step++) {
        long e = (long)(step * 2048 + blockIdx.x) * 256 + threadIdx.x;
        int b = -1;
        int2 sd;
        if (e < E) {
            int src, d;
            if (is64) {
                const int2* p = (const int2*)ei;
                src = p[e].x;
                d = p[E + e].x;
            } else {
                src = ei[e];
                d = ei[E + e];
            }
            if ((unsigned)d < (unsigned)N) {
                b = (int)((unsigned)d / usw);
                sd = make_int2(src, d);
            }
        }
        if (b >= 0) {
            int p = atomicAdd(&lcnt[b], 1);  // max 255 remainder + 256 pushes = 511 < 512
            buf[b][p] = sd;
        }
        __syncthreads();
        for (int k = 0; k < NB; k++) {
            int cnt = lcnt[k];  // uniform (post-barrier)
            if (cnt >= 256) {
                if (threadIdx.x == 0) lbase = atomicAdd(&meta[512 + k * 16], 256);
                __syncthreads();
                bucket[lbase + threadIdx.x] = buf[k][threadIdx.x];
                int rem = cnt - 256;
                int2 r;
                if (threadIdx.x < rem) r = buf[k][256 + threadIdx.x];
                __syncthreads();
                if (threadIdx.x < rem) buf[k][threadIdx.x] = r;
                if (threadIdx.x == 0) lcnt[k] = rem;
                __syncthreads();
            }
        }
    }
    // drain remainders (<256 each)
    for (int k = 0; k < NB; k++) {
        int cnt = lcnt[k];
        if (cnt > 0) {
            if (threadIdx.x == 0) lbase = atomicAdd(&meta[512 + k * 16], cnt);
            __syncthreads();
            if (threadIdx.x < cnt) bucket[lbase + threadIdx.x] = buf[k][threadIdx.x];
            __syncthreads();
        }
    }
}

// ELL build from buckets. One launch per pass; pass p handles slices p*8..p*8+7,
// slice s on XCD (s&7) via blockIdx%8 round-robin: 3.2MB ELL window + 50KB indeg
// stays L2-resident. Bucket stream is truly read-once -> non-temporal.
__global__ __launch_bounds__(256) void k_build2(const int2* __restrict__ bucket,
                                                const int* __restrict__ meta,
                                                int* __restrict__ indeg,
                                                int* __restrict__ ebuf,
                                                int2* __restrict__ spill,
                                                int* __restrict__ flag, int N, int pass) {
    int s = pass * 8 + (blockIdx.x & 7);
    int q = blockIdx.x >> 3;  // 0..511
    int lo = meta[256 + s];
    int hi = meta[288 + s];
    for (int idx = lo + q * 256 + threadIdx.x; idx < hi; idx += 512 * 256) {
        vint2 t = __builtin_nontemporal_load((const vint2*)&bucket[idx]);
        int src = t.x;
        int d = t.y;
        if ((unsigned)src >= (unsigned)N) continue;
        int c = atomicAdd(&indeg[d], 1);
        if (c < ELLS) {
            ebuf[(size_t)d * ELLS + c] = src;
        } else {
            int o = atomicAdd(&flag[2], 1);
            if (o < SPILL_CAP) spill[o] = make_int2(src, d);
        }
    }
}

__global__ void k_dinv(const int* __restrict__ indeg, float* __restrict__ dinv, int n) {
    int i = blockIdx.x * 256 + threadIdx.x;
    if (i < n) dinv[i] = rsqrtf(1.0f + (float)indeg[i]);  // deg includes self loop
}

// convert the 16 weight/bias arrays into one fp32 block; block b handles array b.
struct CW {
    const void* src[16];
    int off[16];
    int n[16];
};
__global__ void k_convw(CW cw, float* __restrict__ dst, const int* __restrict__ flag) {
    int b = blockIdx.x;
    bool isf = flag[0] > 64;
    const float* sf = (const float*)cw.src[b];
    const unsigned short* sh = (const unsigned short*)cw.src[b];
    float* d = dst + cw.off[b];
    int n = cw.n[b];
    for (int i = threadIdx.x; i < n; i += 256) d[i] = isf ? sf[i] : bf2f(sh[i]);
}

// weight-block offsets (floats)
#define O_WG 0
#define O_BG 2500
#define O_WE1 2550
#define O_BE1 4550
#define O_WE2 4590
#define O_BE2 5790
#define O_WE3 5820
#define O_BE3 6420
#define O_WFC 6440
#define O_BFC 6540
#define O_WD1 6550
#define O_BD1 6750
#define O_WD2 6770
#define O_BD2 7570
#define O_WD3 7610
#define O_BD3 9610
#define W_TOT 9660

// g[i] = (x[i,100:150] @ Wg.T) * dinv[i]  -> fp16, stride GS halves; pad zeroed.
__global__ __launch_bounds__(256) void k_g(const void* __restrict__ xv,
                                           const float* __restrict__ W,
                                           const float* __restrict__ dinv,
                                           const int* __restrict__ flag,
                                           _Float16* __restrict__ g16, int n) {
    int i = blockIdx.x * 256 + threadIdx.x;
    if (i >= n) return;
    bool isf = flag[0] > 64;
    float xr[50];
    if (isf) {
        // byte offset (i*150+100)*4 = 600i+400 -> 8B aligned: float2 loads
        const float2* p = (const float2*)((const float*)xv + (size_t)i * 150 + 100);
#pragma unroll
        for (int k = 0; k < 25; k++) {
            float2 q = p[k];
            xr[2 * k] = q.x;
            xr[2 * k + 1] = q.y;
        }
    } else {
        // byte offset (i*150+100)*2 = 300i+200 -> 4B aligned: uint loads (2 bf16)
        const unsigned* p = (const unsigned*)((const unsigned short*)xv + (size_t)i * 150 + 100);
#pragma unroll
        for (int k = 0; k < 25; k++) {
            unsigned u = p[k];
            xr[2 * k] = __uint_as_float(u << 16);
            xr[2 * k + 1] = __uint_as_float(u & 0xFFFF0000u);
        }
    }
    const float* Wg = W + O_WG;
    float di = dinv[i];
    float o[64];
#pragma unroll
    for (int f = 0; f < 50; f += 2) {
        float a0 = 0.f, a1 = 0.f;
#pragma unroll
        for (int p = 0; p < 50; p++) {
            a0 += Wg[f * 50 + p] * xr[p];
            a1 += Wg[(f + 1) * 50 + p] * xr[p];
        }
        o[f] = a0 * di;
        o[f + 1] = a1 * di;
    }
#pragma unroll
    for (int f = 50; f < 64; f++) o[f] = 0.f;
    half8v* gr8 = (half8v*)(g16 + (size_t)i * GS);
#pragma unroll
    for (int p = 0; p < 8; p++) {
        half8v hv;
#pragma unroll
        for (int q = 0; q < 8; q++) hv[q] = (_Float16)o[8 * p + q];
        gr8[p] = hv;
    }
}

// wave per node, 4 edges per instruction: lane=(q,r), q=lane>>4 picks edge slot,
// r=lane&15 picks 8B half4 chunk within the 128B fp16 row. One dwordx2 gathers
// 4 full rows; fp32 accumulate; XOR-reduce over q at the end.
__global__ __launch_bounds__(256) void k_gather(const _Float16* __restrict__ g16,
                                                const int* __restrict__ indeg,
                                                const int* __restrict__ ebuf,
                                                const float* __restrict__ dinv,
                                                const float* __restrict__ W,
                                                float* __restrict__ h1, int n) {
    int wid = threadIdx.x >> 6;
    int lane = threadIdx.x & 63;
    int i = blockIdx.x * 4 + wid;
    if (i >= n) return;
    int q = lane >> 4;
    int r = lane & 15;
    int cnt = indeg[i];
    if (cnt > ELLS) cnt = ELLS;
    int ev = (lane < cnt) ? ebuf[(size_t)i * ELLS + lane] : 0;
    const half4v* g4 = (const half4v*)g16;  // 8B chunks; row = 16 chunks
    float4 a0 = make_float4(0.f, 0.f, 0.f, 0.f);
    float4 a1 = a0, a2 = a0, a3 = a0;
    int m = 0;
    for (; m + 16 <= cnt; m += 16) {
        int j0 = __shfl(ev, m + q);
        int j1 = __shfl(ev, m + 4 + q);
        int j2 = __shfl(ev, m + 8 + q);
        int j3 = __shfl(ev, m + 12 + q);
        half4v t0 = g4[(size_t)j0 * 16 + r];
        half4v t1 = g4[(size_t)j1 * 16 + r];
        half4v t2 = g4[(size_t)j2 * 16 + r];
        half4v t3 = g4[(size_t)j3 * 16 + r];
        a0.x += (float)t0.x; a0.y += (float)t0.y; a0.z += (float)t0.z; a0.w += (float)t0.w;
        a1.x += (float)t1.x; a1.y += (float)t1.y; a1.z += (float)t1.z; a1.w += (float)t1.w;
        a2.x += (float)t2.x; a2.y += (float)t2.y; a2.z += (float)t2.z; a2.w += (float)t2.w;
        a3.x += (float)t3.x; a3.y += (float)t3.y; a3.z += (float)t3.z; a3.w += (float)t3.w;
    }
    for (; m + 4 <= cnt; m += 4) {
        int j = __shfl(ev, m + q);
        half4v t = g4[(size_t)j * 16 + r];
        a0.x += (float)t.x; a0.y += (float)t.y; a0.z += (float)t.z; a0.w += (float)t.w;
    }
    if (m < cnt) {
        int j = __shfl(ev, m + q);
        if (m + q < cnt) {
            half4v t = g4[(size_t)j * 16 + r];
            a0.x += (float)t.x; a0.y += (float)t.y; a0.z += (float)t.z; a0.w += (float)t.w;
        }
    }
    float4 s;
    s.x = (a0.x + a1.x) + (a2.x + a3.x);
    s.y = (a0.y + a1.y) + (a2.y + a3.y);
    s.z = (a0.z + a1.z) + (a2.z + a3.z);
    s.w = (a0.w + a1.w) + (a2.w + a3.w);
    s.x += __shfl_xor(s.x, 16); s.y += __shfl_xor(s.y, 16);
    s.z += __shfl_xor(s.z, 16); s.w += __shfl_xor(s.w, 16);
    s.x += __shfl_xor(s.x, 32); s.y += __shfl_xor(s.y, 32);
    s.z += __shfl_xor(s.z, 32); s.w += __shfl_xor(s.w, 32);
    if (lane < 16) {
        float di = dinv[i];
        half4v self = g4[(size_t)i * 16 + lane];
        float4 b = ((const float4*)(W + O_BG))[lane];  // O_BG*4=10000B, 16B aligned
        float4 h;
        h.x = (s.x + (float)self.x) * di + b.x;
        h.y = (s.y + (float)self.y) * di + b.y;
        h.z = (s.z + (float)self.z) * di + b.z;
        h.w = (s.w + (float)self.w) * di + b.w;
        float* hr = h1 + (size_t)i * HS;
        if (lane < 12) {
            ((float4*)hr)[lane] = h;  // 224B rows: 16B aligned
        } else if (lane == 12) {
            hr[48] = h.x;
            hr[49] = h.y;
        }
    }
}

// overflow edges (deg > ELLS): atomic-add their contribution into h1.
__global__ void k_spill(const int2* __restrict__ spill, const int* __restrict__ flag,
                        const _Float16* __restrict__ g16, const float* __restrict__ dinv,
                        float* __restrict__ h1) {
    int nov = flag[2];
    if (nov > SPILL_CAP) nov = SPILL_CAP;
    int lane = threadIdx.x & 63;
    int wave = (blockIdx.x * 256 + threadIdx.x) >> 6;
    for (int e = wave; e < nov; e += gridDim.x * 4) {
        int2 sd = spill[e];
        if (lane < 50)
            atomicAdd(&h1[(size_t)sd.y * HS + lane],
                      (float)g16[(size_t)sd.x * GS + lane] * dinv[sd.y]);
    }
}

// ---- MLP split: each kernel has <16KB code and <8KB scalar weight stream ----

// e1: t1[i,0:40] = leaky(h1[i,:] @ We1.T + be1)
__global__ __launch_bounds__(256) void k_e1(const float* __restrict__ h1,
                                            const float* __restrict__ W,
                                            float* __restrict__ t1, int n) {
    int i = blockIdx.x * 256 + threadIdx.x;
    if (i >= n) return;
    float v0[50];
    const float* hr = h1 + (size_t)i * HS;
    const float4* hr4 = (const float4*)hr;
#pragma unroll
    for (int p = 0; p < 12; p++) {
        float4 t = hr4[p];
        v0[4 * p] = t.x; v0[4 * p + 1] = t.y; v0[4 * p + 2] = t.z; v0[4 * p + 3] = t.w;
    }
    v0[48] = hr[48];
    v0[49] = hr[49];
    float o[40];
#pragma unroll
    for (int f = 0; f < 40; f++) {
        float a = W[O_BE1 + f];
#pragma unroll
        for (int p = 0; p < 50; p++) a += W[O_WE1 + f * 50 + p] * v0[p];
        o[f] = leaky(a);
    }
    float4* ot = (float4*)(t1 + (size_t)i * 40);
#pragma unroll
    for (int p = 0; p < 10; p++) ot[p] = make_float4(o[4 * p], o[4 * p + 1], o[4 * p + 2], o[4 * p + 3]);
}

// e2+e3: reads t1, writes mu -> out[n*50 + i*10], log_var -> out[n*60 + i*10]
__global__ __launch_bounds__(256) void k_e23(const float* __restrict__ t1,
                                             const float* __restrict__ W,
                                             float* __restrict__ out, int n) {
    int i = blockIdx.x * 256 + threadIdx.x;
    if (i >= n) return;
    float v1[40];
    const float4* tr = (const float4*)(t1 + (size_t)i * 40);
#pragma unroll
    for (int p = 0; p < 10; p++) {
        float4 q = tr[p];
        v1[4 * p] = q.x; v1[4 * p + 1] = q.y; v1[4 * p + 2] = q.z; v1[4 * p + 3] = q.w;
    }
    float v2[30];
#pragma unroll
    for (int f = 0; f < 30; f++) {
        float a = W[O_BE2 + f];
#pragma unroll
        for (int p = 0; p < 40; p++) a += W[O_WE2 + f * 40 + p] * v1[p];
        v2[f] = leaky(a);
    }
    float v3[20];  // [mu(10) | log_var(10)]
#pragma unroll
    for (int f = 0; f < 20; f++) {
        float a = W[O_BE3 + f];
#pragma unroll
        for (int p = 0; p < 30; p++) a += W[O_WE3 + f * 30 + p] * v2[p];
        v3[f] = a;
    }
    float2* o_mu = (float2*)(out + (size_t)n * 50 + (size_t)i * 10);
    float2* o_lv = (float2*)(out + (size_t)n * 60 + (size_t)i * 10);
#pragma unroll
    for (int p = 0; p < 5; p++) {
        o_mu[p] = make_float2(v3[2 * p], v3[2 * p + 1]);
        o_lv[p] = make_float2(v3[10 + 2 * p], v3[10 + 2 * p + 1]);
    }
}

// reparam + fc + d1 + d2: reads mu/log_var from out, eps; writes z -> out[n*70+i*10],
// d2 activations -> t3[i*40] (reuses h1's region).
__global__ __launch_bounds__(256) void k_zfc(float* outb,  // same buffer read+write, disjoint regions
                                             const void* __restrict__ epsv,
                                             const float* __restrict__ W,
                                             const int* __restrict__ flag,
                                             float* __restrict__ t3, int n) {
    int i = blockIdx.x * 256 + threadIdx.x;
    if (i >= n) return;
    bool isf = flag[0] > 64;
    float mu[10], lv[10];
    const float2* pm = (const float2*)(outb + (size_t)n * 50 + (size_t)i * 10);
    const float2* pl = (const float2*)(outb + (size_t)n * 60 + (size_t)i * 10);
#pragma unroll
    for (int p = 0; p < 5; p++) {
        float2 a = pm[p]; mu[2 * p] = a.x; mu[2 * p + 1] = a.y;
        float2 b = pl[p]; lv[2 * p] = b.x; lv[2 * p + 1] = b.y;
    }
    float ev[10];
    if (isf) {
        const float* p = (const float*)epsv + (size_t)i * 10;
#pragma unroll
        for (int k = 0; k < 10; k++) ev[k] = p[k];
    } else {
        const unsigned short* p = (const unsigned short*)epsv + (size_t)i * 10;
#pragma unroll
        for (int k = 0; k < 10; k++) ev[k] = bf2f(p[k]);
    }
    float z1[10];
#pragma unroll
    for (int k = 0; k < 10; k++) z1[k] = mu[k] + ev[k] * expf(0.5f * lv[k]);
    float z[10];
#pragma unroll
    for (int f = 0; f < 10; f++) {
        float a = W[O_BFC + f];
#pragma unroll
        for (int p = 0; p < 10; p++) a += W[O_WFC + f * 10 + p] * z1[p];
        z[f] = (a > 0.f) ? a : 0.f;
    }
    float2* o_z = (float2*)(outb + (size_t)n * 70 + (size_t)i * 10);
#pragma unroll
    for (int p = 0; p < 5; p++) o_z[p] = make_float2(z[2 * p], z[2 * p + 1]);
    float d1[20];
#pragma unroll
    for (int f = 0; f < 20; f++) {
        float a = W[O_BD1 + f];
#pragma unroll
        for (int p = 0; p < 10; p++) a += W[O_WD1 + f * 10 + p] * z[p];
        d1[f] = leaky(a);
    }
    float d2[40];
#pragma unroll
    for (int f = 0; f < 40; f++) {
        float a = W[O_BD2 + f];
#pragma unroll
        for (int p = 0; p < 20; p++) a += W[O_WD2 + f * 20 + p] * d1[p];
        d2[f] = leaky(a);
    }
    float4* ot = (float4*)(t3 + (size_t)i * 40);
#pragma unroll
    for (int p = 0; p < 10; p++)
        ot[p] = make_float4(d2[4 * p], d2[4 * p + 1], d2[4 * p + 2], d2[4 * p + 3]);
}

// d3 + sigmoid: reads t3, writes mu_prime -> out[i*50]
__global__ __launch_bounds__(256) void k_d3(const float* __restrict__ t3,
                                            const float* __restrict__ W,
                                            float* __restrict__ out, int n) {
    int i = blockIdx.x * 256 + threadIdx.x;
    if (i >= n) return;
    float d2[40];
    const float4* tr = (const float4*)(t3 + (size_t)i * 40);
#pragma unroll
    for (int p = 0; p < 10; p++) {
        float4 q = tr[p];
        d2[4 * p] = q.x; d2[4 * p + 1] = q.y; d2[4 * p + 2] = q.z; d2[4 * p + 3] = q.w;
    }
    float o[50];
#pragma unroll
    for (int f = 0; f < 50; f++) {
        float a = W[O_BD3 + f];
#pragma unroll
        for (int p = 0; p < 40; p++) a += W[O_WD3 + f * 40 + p] * d2[p];
        o[f] = 1.f / (1.f + expf(-a));
    }
    float2* om = (float2*)(out + (size_t)i * 50);
#pragma unroll
    for (int p = 0; p < 25; p++) om[p] = make_float2(o[2 * p], o[2 * p + 1]);
}

extern "C" void kernel_launch(void* const* d_in, const int* in_sizes, int n_in,
                              void* d_out, int out_size, void* d_ws, size_t ws_size,
                              hipStream_t stream) {
    const int N = in_sizes[0] / 150;
    const int E = in_sizes[1] / 2;

    char* w = (char*)d_ws;
    auto alloc = [&](size_t bytes) {
        void* p = (void*)w;
        w += (bytes + 255) & ~(size_t)255;
        return p;
    };
    int* indeg = (int*)alloc((size_t)N * 4);
    int* flag = (int*)alloc(256);
    int* meta = (int*)alloc((size_t)META_INTS * 4);
    float* dinv = (float*)alloc((size_t)N * 4);
    float* Wall = (float*)alloc((size_t)W_TOT * 4);
    int2* spill = (int2*)alloc((size_t)SPILL_CAP * 8);
    _Float16* g16 = (_Float16*)alloc((size_t)N * GS * 2);
    float* h1 = (float*)alloc((size_t)N * HS * 4);
    int* ebuf = (int*)alloc((size_t)N * ELLS * 4);

    // bucket (E int2) overlays g16+h1: both are written only after k_build2
    // consumed the buckets. Fallback to fresh alloc if too small.
    int2* bucket;
    if ((size_t)E * 8 <= (size_t)N * GS * 2 + (size_t)N * HS * 4) {
        bucket = (int2*)g16;
    } else {
        bucket = (int2*)alloc((size_t)E * 8);
    }

    // intermediate reuse: t1 (N*40 fp32) in ebuf's region (ebuf dead after
    // k_gather); t3 (N*40) in h1's region (h1 dead after k_e1).
    float* t1 = (float*)ebuf;
    float* t3 = h1;

    CW cw;
    static const int wn[16] = {2500, 50, 2000, 40, 1200, 30, 600, 20,
                               100, 10, 200, 20, 800, 40, 2000, 50};
    static const int wo[16] = {O_WG, O_BG, O_WE1, O_BE1, O_WE2, O_BE2, O_WE3, O_BE3,
                               O_WFC, O_BFC, O_WD1, O_BD1, O_WD2, O_BD2, O_WD3, O_BD3};
    for (int k = 0; k < 16; k++) {
        cw.src[k] = d_in[3 + k];
        cw.off[k] = wo[k];
        cw.n[k] = wn[k];
    }

    int nbN = (N + 255) / 256;

    k_zero<<<nbN, 256, 0, stream>>>(indeg, flag, meta, N);
    k_detect<<<512, 256, 0, stream>>>((const unsigned*)d_in[0], (long)N * 75,
                                      (const unsigned*)d_in[1], (long)E, flag);
    k_hist<<<1024, 256, 0, stream>>>((const int*)d_in[1], flag, meta, E, N);
    k_scan<<<1, 64, 0, stream>>>(meta);
    k_part<<<2048, 256, 0, stream>>>((const int*)d_in[1], flag, meta, bucket, E, N);
    k_build2<<<4096, 256, 0, stream>>>(bucket, meta, indeg, ebuf, spill, flag, N, 0);
    k_build2<<<4096, 256, 0, stream>>>(bucket, meta, indeg, ebuf, spill, flag, N, 1);
    k_dinv<<<nbN, 256, 0, stream>>>(indeg, dinv, N);
    k_convw<<<16, 256, 0, stream>>>(cw, Wall, flag);
    k_g<<<nbN, 256, 0, stream>>>(d_in[0], Wall, dinv, flag, g16, N);
    k_gather<<<(N + 3) / 4, 256, 0, stream>>>(g16, indeg, ebuf, dinv, Wall, h1, N);
    k_spill<<<64, 256, 0, stream>>>(spill, flag, g16, dinv, h1);
    k_e1<<<nbN, 256, 0, stream>>>(h1, Wall, t1, N);
    k_e23<<<nbN, 256, 0, stream>>>(t1, Wall, (float*)d_out, N);
    k_zfc<<<nbN, 256, 0, stream>>>((float*)d_out, d_in[2], Wall, flag, t3, N);
    k_d3<<<nbN, 256, 0, stream>>>(t3, Wall, (float*)d_out, N);
}